// Round 17
// baseline (301.795 us; speedup 1.0000x reference)
//
#include <hip/hip_runtime.h>
#include <hip/hip_bf16.h>

typedef unsigned short u16;
typedef __attribute__((ext_vector_type(8))) short short8;
typedef __attribute__((ext_vector_type(4))) short short4v;
typedef __attribute__((ext_vector_type(8))) u16 u16x8;
typedef __attribute__((ext_vector_type(4))) u16 u16x4;
typedef __attribute__((ext_vector_type(4))) float f32x4;

__device__ __forceinline__ u16 f2bf(float f) {
  __hip_bfloat16 h = __float2bfloat16(f);
  u16 u;
  __builtin_memcpy(&u, &h, 2);
  return u;
}

__device__ __forceinline__ float h2f(u16 h) {
  return (float)__builtin_bit_cast(_Float16, h);
}

__device__ __forceinline__ f32x4 mfma16(short8 a, short8 b, f32x4 c) {
  return __builtin_amdgcn_mfma_f32_16x16x32_bf16(a, b, c, 0, 0, 0);
}

__device__ __forceinline__ f32x4 mfma16x16(short4v a, short4v b, f32x4 c) {
#if __has_builtin(__builtin_amdgcn_mfma_f32_16x16x16bf16_1k)
  return __builtin_amdgcn_mfma_f32_16x16x16bf16_1k(a, b, c, 0, 0, 0);
#else
  asm("v_mfma_f32_16x16x16_bf16 %0, %1, %2, %0" : "+v"(c) : "v"(a), "v"(b));
  return c;
#endif
}

__device__ __forceinline__ void gl_lds16(const void* g, void* l) {
  __builtin_amdgcn_global_load_lds(
      (const __attribute__((address_space(1))) unsigned int*)g,
      (__attribute__((address_space(3))) unsigned int*)l, 16, 0, 0);
}

// ---------------- convert x fp32 -> bf16 (nt streaming write) --------------
__global__ __launch_bounds__(256) void cvt_x_k(const float* __restrict__ x,
                                               u16* __restrict__ xb) {
  int i = (blockIdx.x * 256 + threadIdx.x) * 4;
  float4 v = *(const float4*)(x + i);
  u16x4 o = { f2bf(v.x), f2bf(v.y), f2bf(v.z), f2bf(v.w) };
  __builtin_nontemporal_store(o, (u16x4*)(xb + i));
}

// ------- transpose + convert weight via LDS tile: wt[n][k] = w[k][n] -------
__global__ __launch_bounds__(256) void cvt_wt_k(const float* __restrict__ w,
                                                u16* __restrict__ wt, int N) {
  __shared__ u16 t64[64][65];
  const int n0 = blockIdx.x * 64, k0 = blockIdx.y * 64;
  const int c = threadIdx.x & 63, rg = threadIdx.x >> 6;
#pragma unroll
  for (int r = 0; r < 16; r++) {
    int kk = rg * 16 + r;
    t64[c][kk] = f2bf(w[(size_t)(k0 + kk) * N + n0 + c]);
  }
  __syncthreads();
#pragma unroll
  for (int r = 0; r < 16; r++) {
    int nn = rg * 16 + r;
    __builtin_nontemporal_store(t64[nn][c], wt + (size_t)(n0 + nn) * 768 + k0 + c);
  }
}

// ---------------- CPB bias MLP: 729 entries x (2->512->24), 16*sigmoid -----
__device__ __forceinline__ float cpb_coord(int v) {
  float c = (float)(v - 13) * (8.0f / 13.0f);
  float a = fabsf(c);
  float r = log2f(a + 1.0f) * (1.0f / 3.0f);
  return c < 0.f ? -r : r;
}

__global__ __launch_bounds__(64) void bias_mlp_k(
    const float* __restrict__ w1, const float* __restrict__ b1,
    const float* __restrict__ w2, const float* __restrict__ b2,
    float* __restrict__ btab) {
  int e = blockIdx.x;
  int lane = threadIdx.x;
  float t0 = cpb_coord(e / 27), t1 = cpb_coord(e % 27);
  float acc[24];
#pragma unroll
  for (int hh = 0; hh < 24; hh++) acc[hh] = 0.f;
#pragma unroll
  for (int jj = 0; jj < 8; jj++) {
    int j = lane * 8 + jj;
    float h1 = t0 * w1[j] + t1 * w1[512 + j] + b1[j];
    h1 = fmaxf(h1, 0.f);
#pragma unroll
    for (int hh = 0; hh < 24; hh++) acc[hh] += h1 * w2[j * 24 + hh];
  }
#pragma unroll
  for (int hh = 0; hh < 24; hh++)
#pragma unroll
    for (int m = 1; m < 64; m <<= 1) acc[hh] += __shfl_xor(acc[hh], m, 64);
  if (lane == 0) {
#pragma unroll
    for (int hh = 0; hh < 24; hh++) {
      float v = acc[hh] + b2[hh];
      btab[e * 24 + hh] = 16.f / (1.f + __expf(-v));
    }
  }
}

// --------- expand bias to [24][196][208] f16 bits, pre-scaled by log2e -----
__global__ __launch_bounds__(256) void bias_expand_k(const float* __restrict__ tab,
                                                     u16* __restrict__ be) {
  int i = blockIdx.x * 256 + threadIdx.x;  // 24*196*208
  int h = i / (196 * 208);
  int rem = i % (196 * 208);
  int row = rem / 208, col = rem % 208;
  float v = 0.f;
  if (col < 196) {
    int dy = row / 14 - col / 14 + 13;
    int dx = row % 14 - col % 14 + 13;
    v = tab[(dy * 27 + dx) * 24 + h] * 1.4426950408889634f;
  }
  _Float16 hv = (_Float16)v;
  __builtin_nontemporal_store(__builtin_bit_cast(unsigned short, hv), be + i);
}

// ---------------- GEMM: C = A[M][K] * Bt[N][K]^T + bias -------------------
// 128^2 m97-structure, L2 super-tile + XCD-bijective mapping. THIS ROUND:
// non-temporal C stores — C (113MB qkv / 77MB proj) is never re-read by this
// kernel; keeping it out of L2 preserves A/B panels (measured FETCH 104MB vs
// 42MB compulsory = L2 churn signature).
template <int EPI>
__global__ __launch_bounds__(256) void gemm_k(
    const u16* __restrict__ A, const u16* __restrict__ Bt,
    const float* __restrict__ bias, float* __restrict__ Cf,
    u16* __restrict__ Cb, int N, int K, int nbx) {
  __shared__ u16 As[128 * 64];
  __shared__ u16 Bs[128 * 64];
  const int tid = threadIdx.x, lane = tid & 63, w = tid >> 6;
  const int r16 = lane & 15, q4 = lane >> 4;
  const int wr = w >> 1, wc = w & 1;
  const int nwg = gridDim.x, cpx = nwg >> 3;
  const int swz = (blockIdx.x & 7) * cpx + (blockIdx.x >> 3);
  const int gsz = nbx * 4;
  const int mgrp = swz / gsz, rem = swz % gsz;
  const int m0 = (mgrp * 4 + rem / nbx) * 128, n0 = (rem % nbx) * 128;

  f32x4 acc[4][4] = {};

  for (int k0 = 0; k0 < K; k0 += 64) {
#pragma unroll
    for (int g = 0; g < 4; g++) {
      int chunk = (w * 4 + g) * 64 + lane;
      int row = chunk >> 3, p = chunk & 7;
      int gch = p ^ (row & 7);
      gl_lds16(A + (size_t)(m0 + row) * K + k0 + gch * 8, (char*)As + (w * 4 + g) * 1024);
      gl_lds16(Bt + (size_t)(n0 + row) * K + k0 + gch * 8, (char*)Bs + (w * 4 + g) * 1024);
    }
    __syncthreads();
#pragma unroll
    for (int kk = 0; kk < 2; kk++) {
      short8 af[4], bfr[4];
#pragma unroll
      for (int i = 0; i < 4; i++) {
        int row = wr * 64 + i * 16 + r16;
        int pc = (kk * 4 + q4) ^ (r16 & 7);
        af[i] = *(const short8*)((const char*)As + row * 128 + pc * 16);
      }
#pragma unroll
      for (int j = 0; j < 4; j++) {
        int row = wc * 64 + j * 16 + r16;
        int pc = (kk * 4 + q4) ^ (r16 & 7);
        bfr[j] = *(const short8*)((const char*)Bs + row * 128 + pc * 16);
      }
#pragma unroll
      for (int i = 0; i < 4; i++)
#pragma unroll
        for (int j = 0; j < 4; j++) acc[i][j] = mfma16(af[i], bfr[j], acc[i][j]);
    }
    __syncthreads();
  }

  const int nb = n0 + wc * 64 + r16;
  float bn[4];
#pragma unroll
  for (int j = 0; j < 4; j++) bn[j] = bias[nb + j * 16];
#pragma unroll
  for (int i = 0; i < 4; i++) {
#pragma unroll
    for (int r = 0; r < 4; r++) {
      int m = m0 + wr * 64 + i * 16 + q4 * 4 + r;
      if (EPI == 1) {
        float* cp = Cf + (size_t)m * N + nb;
#pragma unroll
        for (int j = 0; j < 4; j++)
          __builtin_nontemporal_store(acc[i][j][r] + bn[j], cp + j * 16);
      } else {
        u16* cp = Cb + (size_t)m * N + nb;
#pragma unroll
        for (int j = 0; j < 4; j++)
          __builtin_nontemporal_store(f2bf(acc[i][j][r] + bn[j]), cp + j * 16);
      }
    }
  }
}

// ---------------- attention: one block per (b,h) --------------------------
// Swapped QK^T -> P lane-local -> PV via 16x16x16 MFMA. No-max softmax;
// 1/sum deferred with row-transposing shuffle; k-half split; f16 bias
// hoisted. O-writes now non-temporal (never re-read before proj streams it).
__global__ __launch_bounds__(256) void attn_k(
    const u16* __restrict__ qkv, const u16* __restrict__ be,
    u16* __restrict__ ao) {
  constexpr int VST = 236;
  __shared__ u16 Ks[208 * 32];
  __shared__ u16 Vt[32 * VST];
  const int tid = threadIdx.x, lane = tid & 63, w = tid >> 6;
  const int r16 = lane & 15, q4 = lane >> 4;
  const int bh = blockIdx.x, b = bh / 24, h = bh % 24;
  const u16* qp = qkv + (size_t)(b * 196) * 2304 + h * 32;
  const u16* kp = qp + 768;
  const u16* vp = qp + 1536;
  const u16* bp = be + h * (196 * 208);
  const int ksw = (q4 ^ ((r16 >> 1) & 3)) * 16;
  const float SC2 = 0.17677669529663687f * 1.4426950408889634f;

  for (int g = w; g < 13; g += 4) {
    int chunk = g * 64 + lane;
    int row = chunk >> 2;
    int gch = (chunk & 3) ^ ((row >> 1) & 3);
    gl_lds16(kp + (size_t)row * 2304 + gch * 8, (char*)Ks + g * 1024);
  }
  for (int c = tid; c < 784; c += 256) {
    int n = c >> 2, d0 = (c & 3) * 8;
    u16x8 vv = *(const u16x8*)(vp + (size_t)n * 2304 + (c & 3) * 8);
#pragma unroll
    for (int jj = 0; jj < 8; jj++) Vt[(d0 + jj) * VST + n] = vv[jj];
  }
  for (int idx = tid; idx < 32 * 40; idx += 256) {
    int d = idx / 40, n = 196 + idx % 40;
    Vt[d * VST + n] = 0;
  }
  __syncthreads();

  const f32x4 z = {0.f, 0.f, 0.f, 0.f};
  short8 bq = *(const short8*)(qp + (size_t)(w * 16 + r16) * 2304 + q4 * 8);
  for (int si = w; si < 13; si += 4) {
    short8 bq_next = {};
    if (si + 4 < 13)
      bq_next = *(const short8*)(qp + (size_t)((si + 4) * 16 + r16) * 2304 + q4 * 8);
    int gc = si * 16 + r16;
    gc = gc < 196 ? gc : 195;
    const u16* browh = bp + gc * 208 + q4 * 4;
    float s0 = 0.f, s1 = 0.f, s2 = 0.f, s3 = 0.f;
    f32x4 o0a = z, o0b = z, o1a = z, o1b = z;

    // ---- half 0: tiles 0..6 (no masking: max key 111 < 196) ----
    {
      short4v pa[7];
#pragma unroll
      for (int t = 0; t < 7; t++) {
        short8 ka = *(const short8*)((const char*)Ks + (t * 16 + r16) * 64 + ksw);
        f32x4 p = mfma16(ka, bq, z);
        u16x4 bv = *(const u16x4*)(browh + t * 16);
        float e0 = __builtin_amdgcn_exp2f(p[0] * SC2 + h2f(bv[0]));
        float e1 = __builtin_amdgcn_exp2f(p[1] * SC2 + h2f(bv[1]));
        float e2 = __builtin_amdgcn_exp2f(p[2] * SC2 + h2f(bv[2]));
        float e3 = __builtin_amdgcn_exp2f(p[3] * SC2 + h2f(bv[3]));
        s0 += e0; s1 += e1; s2 += e2; s3 += e3;
        pa[t][0] = (short)f2bf(e0);
        pa[t][1] = (short)f2bf(e1);
        pa[t][2] = (short)f2bf(e2);
        pa[t][3] = (short)f2bf(e3);
      }
      __builtin_amdgcn_s_setprio(1);
#pragma unroll
      for (int t = 0; t < 7; t++) {
        const u16* vrow = &Vt[r16 * VST + t * 16 + q4 * 4];
        short4v b0 = *(const short4v*)vrow;
        short4v b1 = *(const short4v*)(vrow + 16 * VST);
        if (t & 1) {
          o0b = mfma16x16(pa[t], b0, o0b);
          o1b = mfma16x16(pa[t], b1, o1b);
        } else {
          o0a = mfma16x16(pa[t], b0, o0a);
          o1a = mfma16x16(pa[t], b1, o1a);
        }
      }
      __builtin_amdgcn_s_setprio(0);
    }
    // ---- half 1: tiles 7..12 (mask only t=12: keys 192..207) ----
    {
      short4v pa[6];
#pragma unroll
      for (int t2 = 0; t2 < 6; t2++) {
        const int t = 7 + t2;
        short8 ka = *(const short8*)((const char*)Ks + (t * 16 + r16) * 64 + ksw);
        f32x4 p = mfma16(ka, bq, z);
        u16x4 bv = *(const u16x4*)(browh + t * 16);
        float e0 = __builtin_amdgcn_exp2f(p[0] * SC2 + h2f(bv[0]));
        float e1 = __builtin_amdgcn_exp2f(p[1] * SC2 + h2f(bv[1]));
        float e2 = __builtin_amdgcn_exp2f(p[2] * SC2 + h2f(bv[2]));
        float e3 = __builtin_amdgcn_exp2f(p[3] * SC2 + h2f(bv[3]));
        if (t == 12) {
          int k0 = 192 + q4 * 4;
          e0 = (k0 + 0 < 196) ? e0 : 0.f;
          e1 = (k0 + 1 < 196) ? e1 : 0.f;
          e2 = (k0 + 2 < 196) ? e2 : 0.f;
          e3 = (k0 + 3 < 196) ? e3 : 0.f;
        }
        s0 += e0; s1 += e1; s2 += e2; s3 += e3;
        pa[t2][0] = (short)f2bf(e0);
        pa[t2][1] = (short)f2bf(e1);
        pa[t2][2] = (short)f2bf(e2);
        pa[t2][3] = (short)f2bf(e3);
      }
      __builtin_amdgcn_s_setprio(1);
#pragma unroll
      for (int t2 = 0; t2 < 6; t2++) {
        const int t = 7 + t2;
        const u16* vrow = &Vt[r16 * VST + t * 16 + q4 * 4];
        short4v b0 = *(const short4v*)vrow;
        short4v b1 = *(const short4v*)(vrow + 16 * VST);
        if (t2 & 1) {
          o0b = mfma16x16(pa[t2], b0, o0b);
          o1b = mfma16x16(pa[t2], b1, o1b);
        } else {
          o0a = mfma16x16(pa[t2], b0, o0a);
          o1a = mfma16x16(pa[t2], b1, o1a);
        }
      }
      __builtin_amdgcn_s_setprio(0);
    }

    bq = bq_next;
    float sum = (s0 + s1) + (s2 + s3);
    sum += __shfl_xor(sum, 16, 64);
    sum += __shfl_xor(sum, 32, 64);
    float rs = 1.0f / sum;
#pragma unroll
    for (int r = 0; r < 4; r++) {
      float rsv = __shfl(rs, q4 * 4 + r, 16);
      int grow = si * 16 + q4 * 4 + r;
      if (grow < 196) {
        u16* op = ao + ((size_t)(b * 196 + grow)) * 768 + h * 32;
        __builtin_nontemporal_store(f2bf((o0a[r] + o0b[r]) * rsv), op + r16);
        __builtin_nontemporal_store(f2bf((o1a[r] + o1b[r]) * rsv), op + 16 + r16);
      }
    }
  }
}

// ---------------------------------------------------------------------------
extern "C" void kernel_launch(void* const* d_in, const int* in_sizes, int n_in,
                              void* d_out, int out_size, void* d_ws, size_t ws_size,
                              hipStream_t stream) {
  const float* x = (const float*)d_in[0];
  const float* qkv_w = (const float*)d_in[1];
  const float* qkv_b = (const float*)d_in[2];
  const float* proj_w = (const float*)d_in[3];
  const float* proj_b = (const float*)d_in[4];
  const float* cpb_w1 = (const float*)d_in[5];
  const float* cpb_b1 = (const float*)d_in[6];
  const float* cpb_w2 = (const float*)d_in[7];
  const float* cpb_b2 = (const float*)d_in[8];
  float* out = (float*)d_out;

  char* ws = (char*)d_ws;
  size_t o = 0;
  auto alloc = [&](size_t sz) {
    size_t r = o;
    o = (o + sz + 255) & ~(size_t)255;
    return r;
  };
  const size_t ME = (size_t)25088 * 768;
  u16* x_bf = (u16*)(ws + alloc(ME * 2));           // also aliased as attnout
  u16* wq_t = (u16*)(ws + alloc((size_t)2304 * 768 * 2));
  u16* wp_t = (u16*)(ws + alloc((size_t)768 * 768 * 2));
  u16* qkv_s = (u16*)(ws + alloc(3 * ME * 2));      // [25088][2304] bf16
  float* btab = (float*)(ws + alloc((size_t)729 * 24 * 4));
  u16* bexp = (u16*)(ws + alloc((size_t)24 * 196 * 208 * 2));  // f16 bits
  u16* ao = x_bf;

  cvt_x_k<<<18816, 256, 0, stream>>>(x, x_bf);
  cvt_wt_k<<<dim3(36, 12), 256, 0, stream>>>(qkv_w, wq_t, 2304);
  cvt_wt_k<<<dim3(12, 12), 256, 0, stream>>>(proj_w, wp_t, 768);
  bias_mlp_k<<<729, 64, 0, stream>>>(cpb_w1, cpb_b1, cpb_w2, cpb_b2, btab);
  bias_expand_k<<<3822, 256, 0, stream>>>(btab, bexp);
  gemm_k<0><<<3528, 256, 0, stream>>>(x_bf, wq_t, qkv_b, nullptr, qkv_s,
                                      2304, 768, 18);
  attn_k<<<3072, 256, 0, stream>>>(qkv_s, bexp, ao);
  gemm_k<1><<<1176, 256, 0, stream>>>(ao, wp_t, proj_b, out, nullptr,
                                      768, 768, 6);
}

// Round 18
// 264.327 us; speedup vs baseline: 1.1417x; 1.1417x over previous
//
#include <hip/hip_runtime.h>
#include <hip/hip_bf16.h>

typedef unsigned short u16;
typedef __attribute__((ext_vector_type(8))) short short8;
typedef __attribute__((ext_vector_type(4))) short short4v;
typedef __attribute__((ext_vector_type(8))) u16 u16x8;
typedef __attribute__((ext_vector_type(4))) u16 u16x4;
typedef __attribute__((ext_vector_type(4))) float f32x4;

__device__ __forceinline__ u16 f2bf(float f) {
  __hip_bfloat16 h = __float2bfloat16(f);
  u16 u;
  __builtin_memcpy(&u, &h, 2);
  return u;
}

__device__ __forceinline__ float h2f(u16 h) {
  return (float)__builtin_bit_cast(_Float16, h);
}

__device__ __forceinline__ f32x4 mfma16(short8 a, short8 b, f32x4 c) {
  return __builtin_amdgcn_mfma_f32_16x16x32_bf16(a, b, c, 0, 0, 0);
}

__device__ __forceinline__ f32x4 mfma16x16(short4v a, short4v b, f32x4 c) {
#if __has_builtin(__builtin_amdgcn_mfma_f32_16x16x16bf16_1k)
  return __builtin_amdgcn_mfma_f32_16x16x16bf16_1k(a, b, c, 0, 0, 0);
#else
  asm("v_mfma_f32_16x16x16_bf16 %0, %1, %2, %0" : "+v"(c) : "v"(a), "v"(b));
  return c;
#endif
}

__device__ __forceinline__ void gl_lds16(const void* g, void* l) {
  __builtin_amdgcn_global_load_lds(
      (const __attribute__((address_space(1))) unsigned int*)g,
      (__attribute__((address_space(3))) unsigned int*)l, 16, 0, 0);
}

// ---------------- convert x fp32 -> bf16 ----------------
__global__ __launch_bounds__(256) void cvt_x_k(const float* __restrict__ x,
                                               u16* __restrict__ xb) {
  int i = (blockIdx.x * 256 + threadIdx.x) * 4;
  float4 v = *(const float4*)(x + i);
  u16x4 o = { f2bf(v.x), f2bf(v.y), f2bf(v.z), f2bf(v.w) };
  *(u16x4*)(xb + i) = o;
}

// ------- transpose + convert weight via LDS tile: wt[n][k] = w[k][n] -------
__global__ __launch_bounds__(256) void cvt_wt_k(const float* __restrict__ w,
                                                u16* __restrict__ wt, int N) {
  __shared__ u16 t64[64][65];
  const int n0 = blockIdx.x * 64, k0 = blockIdx.y * 64;
  const int c = threadIdx.x & 63, rg = threadIdx.x >> 6;
#pragma unroll
  for (int r = 0; r < 16; r++) {
    int kk = rg * 16 + r;
    t64[c][kk] = f2bf(w[(size_t)(k0 + kk) * N + n0 + c]);
  }
  __syncthreads();
#pragma unroll
  for (int r = 0; r < 16; r++) {
    int nn = rg * 16 + r;
    wt[(size_t)(n0 + nn) * 768 + k0 + c] = t64[nn][c];
  }
}

// ---------------- CPB bias MLP: 729 entries x (2->512->24), 16*sigmoid -----
__device__ __forceinline__ float cpb_coord(int v) {
  float c = (float)(v - 13) * (8.0f / 13.0f);
  float a = fabsf(c);
  float r = log2f(a + 1.0f) * (1.0f / 3.0f);
  return c < 0.f ? -r : r;
}

__global__ __launch_bounds__(64) void bias_mlp_k(
    const float* __restrict__ w1, const float* __restrict__ b1,
    const float* __restrict__ w2, const float* __restrict__ b2,
    float* __restrict__ btab) {
  int e = blockIdx.x;
  int lane = threadIdx.x;
  float t0 = cpb_coord(e / 27), t1 = cpb_coord(e % 27);
  float acc[24];
#pragma unroll
  for (int hh = 0; hh < 24; hh++) acc[hh] = 0.f;
#pragma unroll
  for (int jj = 0; jj < 8; jj++) {
    int j = lane * 8 + jj;
    float h1 = t0 * w1[j] + t1 * w1[512 + j] + b1[j];
    h1 = fmaxf(h1, 0.f);
#pragma unroll
    for (int hh = 0; hh < 24; hh++) acc[hh] += h1 * w2[j * 24 + hh];
  }
#pragma unroll
  for (int hh = 0; hh < 24; hh++)
#pragma unroll
    for (int m = 1; m < 64; m <<= 1) acc[hh] += __shfl_xor(acc[hh], m, 64);
  if (lane == 0) {
#pragma unroll
    for (int hh = 0; hh < 24; hh++) {
      float v = acc[hh] + b2[hh];
      btab[e * 24 + hh] = 16.f / (1.f + __expf(-v));
    }
  }
}

// --------- expand bias to [24][196][208] f16 bits, pre-scaled by log2e -----
__global__ __launch_bounds__(256) void bias_expand_k(const float* __restrict__ tab,
                                                     u16* __restrict__ be) {
  int i = blockIdx.x * 256 + threadIdx.x;  // 24*196*208
  int h = i / (196 * 208);
  int rem = i % (196 * 208);
  int row = rem / 208, col = rem % 208;
  float v = 0.f;
  if (col < 196) {
    int dy = row / 14 - col / 14 + 13;
    int dx = row % 14 - col % 14 + 13;
    v = tab[(dy * 27 + dx) * 24 + h] * 1.4426950408889634f;
  }
  _Float16 hv = (_Float16)v;
  be[i] = __builtin_bit_cast(unsigned short, hv);
}

// ---------------- GEMM: C = A[M][K] * Bt[N][K]^T + bias -------------------
// 128^2 m97-structure, L2 super-tile + XCD-bijective mapping. Plain stores:
// NT stores were tried (R17) — FETCH dropped 104->71MB as predicted but dur
// ROSE 112->130us: L2 write-combining of the 2B-granular bf16 epilogue was
// load-bearing. The A/B re-fetch is NOT on the critical path; kernel is
// structure-bound (MfmaUtil 35% = MFMA-floor/dur, VALUBusy 50%).
template <int EPI>
__global__ __launch_bounds__(256) void gemm_k(
    const u16* __restrict__ A, const u16* __restrict__ Bt,
    const float* __restrict__ bias, float* __restrict__ Cf,
    u16* __restrict__ Cb, int N, int K, int nbx) {
  __shared__ u16 As[128 * 64];
  __shared__ u16 Bs[128 * 64];
  const int tid = threadIdx.x, lane = tid & 63, w = tid >> 6;
  const int r16 = lane & 15, q4 = lane >> 4;
  const int wr = w >> 1, wc = w & 1;
  const int nwg = gridDim.x, cpx = nwg >> 3;
  const int swz = (blockIdx.x & 7) * cpx + (blockIdx.x >> 3);
  const int gsz = nbx * 4;
  const int mgrp = swz / gsz, rem = swz % gsz;
  const int m0 = (mgrp * 4 + rem / nbx) * 128, n0 = (rem % nbx) * 128;

  f32x4 acc[4][4] = {};

  for (int k0 = 0; k0 < K; k0 += 64) {
#pragma unroll
    for (int g = 0; g < 4; g++) {
      int chunk = (w * 4 + g) * 64 + lane;
      int row = chunk >> 3, p = chunk & 7;
      int gch = p ^ (row & 7);
      gl_lds16(A + (size_t)(m0 + row) * K + k0 + gch * 8, (char*)As + (w * 4 + g) * 1024);
      gl_lds16(Bt + (size_t)(n0 + row) * K + k0 + gch * 8, (char*)Bs + (w * 4 + g) * 1024);
    }
    __syncthreads();
#pragma unroll
    for (int kk = 0; kk < 2; kk++) {
      short8 af[4], bfr[4];
#pragma unroll
      for (int i = 0; i < 4; i++) {
        int row = wr * 64 + i * 16 + r16;
        int pc = (kk * 4 + q4) ^ (r16 & 7);
        af[i] = *(const short8*)((const char*)As + row * 128 + pc * 16);
      }
#pragma unroll
      for (int j = 0; j < 4; j++) {
        int row = wc * 64 + j * 16 + r16;
        int pc = (kk * 4 + q4) ^ (r16 & 7);
        bfr[j] = *(const short8*)((const char*)Bs + row * 128 + pc * 16);
      }
#pragma unroll
      for (int i = 0; i < 4; i++)
#pragma unroll
        for (int j = 0; j < 4; j++) acc[i][j] = mfma16(af[i], bfr[j], acc[i][j]);
    }
    __syncthreads();
  }

  const int nb = n0 + wc * 64 + r16;
  float bn[4];
#pragma unroll
  for (int j = 0; j < 4; j++) bn[j] = bias[nb + j * 16];
#pragma unroll
  for (int i = 0; i < 4; i++) {
#pragma unroll
    for (int r = 0; r < 4; r++) {
      int m = m0 + wr * 64 + i * 16 + q4 * 4 + r;
      if (EPI == 1) {
        float* cp = Cf + (size_t)m * N + nb;
#pragma unroll
        for (int j = 0; j < 4; j++) cp[j * 16] = acc[i][j][r] + bn[j];
      } else {
        u16* cp = Cb + (size_t)m * N + nb;
#pragma unroll
        for (int j = 0; j < 4; j++) cp[j * 16] = f2bf(acc[i][j][r] + bn[j]);
      }
    }
  }
}

// ---------------- attention: one block per (b,h) --------------------------
// Swapped QK^T -> P lane-local -> PV via 16x16x16 MFMA. No-max softmax;
// 1/sum deferred with row-transposing shuffle; k-half split; f16 bias
// hoisted. Plain O stores (NT regressed, R17).
__global__ __launch_bounds__(256) void attn_k(
    const u16* __restrict__ qkv, const u16* __restrict__ be,
    u16* __restrict__ ao) {
  constexpr int VST = 236;
  __shared__ u16 Ks[208 * 32];
  __shared__ u16 Vt[32 * VST];
  const int tid = threadIdx.x, lane = tid & 63, w = tid >> 6;
  const int r16 = lane & 15, q4 = lane >> 4;
  const int bh = blockIdx.x, b = bh / 24, h = bh % 24;
  const u16* qp = qkv + (size_t)(b * 196) * 2304 + h * 32;
  const u16* kp = qp + 768;
  const u16* vp = qp + 1536;
  const u16* bp = be + h * (196 * 208);
  const int ksw = (q4 ^ ((r16 >> 1) & 3)) * 16;
  const float SC2 = 0.17677669529663687f * 1.4426950408889634f;

  for (int g = w; g < 13; g += 4) {
    int chunk = g * 64 + lane;
    int row = chunk >> 2;
    int gch = (chunk & 3) ^ ((row >> 1) & 3);
    gl_lds16(kp + (size_t)row * 2304 + gch * 8, (char*)Ks + g * 1024);
  }
  for (int c = tid; c < 784; c += 256) {
    int n = c >> 2, d0 = (c & 3) * 8;
    u16x8 vv = *(const u16x8*)(vp + (size_t)n * 2304 + (c & 3) * 8);
#pragma unroll
    for (int jj = 0; jj < 8; jj++) Vt[(d0 + jj) * VST + n] = vv[jj];
  }
  for (int idx = tid; idx < 32 * 40; idx += 256) {
    int d = idx / 40, n = 196 + idx % 40;
    Vt[d * VST + n] = 0;
  }
  __syncthreads();

  const f32x4 z = {0.f, 0.f, 0.f, 0.f};
  short8 bq = *(const short8*)(qp + (size_t)(w * 16 + r16) * 2304 + q4 * 8);
  for (int si = w; si < 13; si += 4) {
    short8 bq_next = {};
    if (si + 4 < 13)
      bq_next = *(const short8*)(qp + (size_t)((si + 4) * 16 + r16) * 2304 + q4 * 8);
    int gc = si * 16 + r16;
    gc = gc < 196 ? gc : 195;
    const u16* browh = bp + gc * 208 + q4 * 4;
    float s0 = 0.f, s1 = 0.f, s2 = 0.f, s3 = 0.f;
    f32x4 o0a = z, o0b = z, o1a = z, o1b = z;

    // ---- half 0: tiles 0..6 (no masking: max key 111 < 196) ----
    {
      short4v pa[7];
#pragma unroll
      for (int t = 0; t < 7; t++) {
        short8 ka = *(const short8*)((const char*)Ks + (t * 16 + r16) * 64 + ksw);
        f32x4 p = mfma16(ka, bq, z);
        u16x4 bv = *(const u16x4*)(browh + t * 16);
        float e0 = __builtin_amdgcn_exp2f(p[0] * SC2 + h2f(bv[0]));
        float e1 = __builtin_amdgcn_exp2f(p[1] * SC2 + h2f(bv[1]));
        float e2 = __builtin_amdgcn_exp2f(p[2] * SC2 + h2f(bv[2]));
        float e3 = __builtin_amdgcn_exp2f(p[3] * SC2 + h2f(bv[3]));
        s0 += e0; s1 += e1; s2 += e2; s3 += e3;
        pa[t][0] = (short)f2bf(e0);
        pa[t][1] = (short)f2bf(e1);
        pa[t][2] = (short)f2bf(e2);
        pa[t][3] = (short)f2bf(e3);
      }
      __builtin_amdgcn_s_setprio(1);
#pragma unroll
      for (int t = 0; t < 7; t++) {
        const u16* vrow = &Vt[r16 * VST + t * 16 + q4 * 4];
        short4v b0 = *(const short4v*)vrow;
        short4v b1 = *(const short4v*)(vrow + 16 * VST);
        if (t & 1) {
          o0b = mfma16x16(pa[t], b0, o0b);
          o1b = mfma16x16(pa[t], b1, o1b);
        } else {
          o0a = mfma16x16(pa[t], b0, o0a);
          o1a = mfma16x16(pa[t], b1, o1a);
        }
      }
      __builtin_amdgcn_s_setprio(0);
    }
    // ---- half 1: tiles 7..12 (mask only t=12: keys 192..207) ----
    {
      short4v pa[6];
#pragma unroll
      for (int t2 = 0; t2 < 6; t2++) {
        const int t = 7 + t2;
        short8 ka = *(const short8*)((const char*)Ks + (t * 16 + r16) * 64 + ksw);
        f32x4 p = mfma16(ka, bq, z);
        u16x4 bv = *(const u16x4*)(browh + t * 16);
        float e0 = __builtin_amdgcn_exp2f(p[0] * SC2 + h2f(bv[0]));
        float e1 = __builtin_amdgcn_exp2f(p[1] * SC2 + h2f(bv[1]));
        float e2 = __builtin_amdgcn_exp2f(p[2] * SC2 + h2f(bv[2]));
        float e3 = __builtin_amdgcn_exp2f(p[3] * SC2 + h2f(bv[3]));
        if (t == 12) {
          int k0 = 192 + q4 * 4;
          e0 = (k0 + 0 < 196) ? e0 : 0.f;
          e1 = (k0 + 1 < 196) ? e1 : 0.f;
          e2 = (k0 + 2 < 196) ? e2 : 0.f;
          e3 = (k0 + 3 < 196) ? e3 : 0.f;
        }
        s0 += e0; s1 += e1; s2 += e2; s3 += e3;
        pa[t2][0] = (short)f2bf(e0);
        pa[t2][1] = (short)f2bf(e1);
        pa[t2][2] = (short)f2bf(e2);
        pa[t2][3] = (short)f2bf(e3);
      }
      __builtin_amdgcn_s_setprio(1);
#pragma unroll
      for (int t2 = 0; t2 < 6; t2++) {
        const int t = 7 + t2;
        const u16* vrow = &Vt[r16 * VST + t * 16 + q4 * 4];
        short4v b0 = *(const short4v*)vrow;
        short4v b1 = *(const short4v*)(vrow + 16 * VST);
        if (t2 & 1) {
          o0b = mfma16x16(pa[t2], b0, o0b);
          o1b = mfma16x16(pa[t2], b1, o1b);
        } else {
          o0a = mfma16x16(pa[t2], b0, o0a);
          o1a = mfma16x16(pa[t2], b1, o1a);
        }
      }
      __builtin_amdgcn_s_setprio(0);
    }

    bq = bq_next;
    float sum = (s0 + s1) + (s2 + s3);
    sum += __shfl_xor(sum, 16, 64);
    sum += __shfl_xor(sum, 32, 64);
    float rs = 1.0f / sum;
#pragma unroll
    for (int r = 0; r < 4; r++) {
      float rsv = __shfl(rs, q4 * 4 + r, 16);
      int grow = si * 16 + q4 * 4 + r;
      if (grow < 196) {
        u16* op = ao + ((size_t)(b * 196 + grow)) * 768 + h * 32;
        op[r16] = f2bf((o0a[r] + o0b[r]) * rsv);
        op[16 + r16] = f2bf((o1a[r] + o1b[r]) * rsv);
      }
    }
  }
}

// ---------------------------------------------------------------------------
extern "C" void kernel_launch(void* const* d_in, const int* in_sizes, int n_in,
                              void* d_out, int out_size, void* d_ws, size_t ws_size,
                              hipStream_t stream) {
  const float* x = (const float*)d_in[0];
  const float* qkv_w = (const float*)d_in[1];
  const float* qkv_b = (const float*)d_in[2];
  const float* proj_w = (const float*)d_in[3];
  const float* proj_b = (const float*)d_in[4];
  const float* cpb_w1 = (const float*)d_in[5];
  const float* cpb_b1 = (const float*)d_in[6];
  const float* cpb_w2 = (const float*)d_in[7];
  const float* cpb_b2 = (const float*)d_in[8];
  float* out = (float*)d_out;

  char* ws = (char*)d_ws;
  size_t o = 0;
  auto alloc = [&](size_t sz) {
    size_t r = o;
    o = (o + sz + 255) & ~(size_t)255;
    return r;
  };
  const size_t ME = (size_t)25088 * 768;
  u16* x_bf = (u16*)(ws + alloc(ME * 2));           // also aliased as attnout
  u16* wq_t = (u16*)(ws + alloc((size_t)2304 * 768 * 2));
  u16* wp_t = (u16*)(ws + alloc((size_t)768 * 768 * 2));
  u16* qkv_s = (u16*)(ws + alloc(3 * ME * 2));      // [25088][2304] bf16
  float* btab = (float*)(ws + alloc((size_t)729 * 24 * 4));
  u16* bexp = (u16*)(ws + alloc((size_t)24 * 196 * 208 * 2));  // f16 bits
  u16* ao = x_bf;

  cvt_x_k<<<18816, 256, 0, stream>>>(x, x_bf);
  cvt_wt_k<<<dim3(36, 12), 256, 0, stream>>>(qkv_w, wq_t, 2304);
  cvt_wt_k<<<dim3(12, 12), 256, 0, stream>>>(proj_w, wp_t, 768);
  bias_mlp_k<<<729, 64, 0, stream>>>(cpb_w1, cpb_b1, cpb_w2, cpb_b2, btab);
  bias_expand_k<<<3822, 256, 0, stream>>>(btab, bexp);
  gemm_k<0><<<3528, 256, 0, stream>>>(x_bf, wq_t, qkv_b, nullptr, qkv_s,
                                      2304, 768, 18);
  attn_k<<<3072, 256, 0, stream>>>(qkv_s, bexp, ao);
  gemm_k<1><<<1176, 256, 0, stream>>>(ao, wp_t, proj_b, out, nullptr,
                                      768, 768, 6);
}